// Round 7
// baseline (272.855 us; speedup 1.0000x reference)
//
#include <hip/hip_runtime.h>
#include <math.h>
#include <stdint.h>

// B=4, C=256, H=W=64 -> HW=4096, C4=64
#define HWN 4096
#define CIN 256
#define CQ 64
#define LOG2E 1.44269504f
#define C2OFF 56.0f    // fixed softmax offset (exp2 domain); P kept in bf16
                       // (fp32 exponent range) -> tail-query underflow impossible

typedef __attribute__((ext_vector_type(8))) _Float16 f16x8;
typedef __attribute__((ext_vector_type(8))) short    bf16x8;
typedef __attribute__((ext_vector_type(4))) short    bf16x4;
typedef __attribute__((ext_vector_type(4))) float    f32x4;

__device__ __forceinline__ short f2bf(float f) {
  union { float f; uint32_t u; } c; c.f = f;
  uint32_t r = (c.u + 0x7FFFu + ((c.u >> 16) & 1u)) >> 16;   // RNE
  return (short)(uint16_t)r;
}

// ---------------------------------------------------------------- prep ----
__global__ __launch_bounds__(256) void prep_kernel(
    const float* __restrict__ Wqk, const float* __restrict__ Wkl,
    const float* __restrict__ Wkf, const float* __restrict__ Wv,
    const float* __restrict__ Wfire, const float* __restrict__ bfire,
    const float* __restrict__ gamma, const float* __restrict__ beta,
    const float* __restrict__ mean,  const float* __restrict__ var,
    _Float16* __restrict__ wqk_h, _Float16* __restrict__ wkl_h,
    _Float16* __restrict__ wkf_h, _Float16* __restrict__ wv_h,
    _Float16* __restrict__ wf_h, float* __restrict__ scale, float* __restrict__ shift) {
  int gid = blockIdx.x * 256 + threadIdx.x;
  if (gid < CQ * CIN) {
    wqk_h[gid] = (_Float16)(Wqk[gid] * LOG2E);
    wkl_h[gid] = (_Float16)Wkl[gid];
    wkf_h[gid] = (_Float16)Wkf[gid];
    wv_h[gid]  = (_Float16)Wv[gid];
  }
  if (gid < CIN * 128) wf_h[gid] = (_Float16)Wfire[gid];
  if (gid < CIN) {
    float inv = gamma[gid] / sqrtf(var[gid] + 1e-5f);
    scale[gid] = inv;
    shift[gid] = (bfire[gid] - mean[gid]) * inv + beta[gid];
  }
}

// ---------------------------------------------------------------- proj ----
// (unchanged from R6) 3 passes: cur->q+v; last->kl; fut->kf. Grid 768.
__global__ __launch_bounds__(256) void proj_kernel(
    const float* __restrict__ cur, const float* __restrict__ last, const float* __restrict__ fut,
    const _Float16* __restrict__ wqk, const float* __restrict__ bqk,
    const _Float16* __restrict__ wkl, const float* __restrict__ bkl,
    const _Float16* __restrict__ wkf, const float* __restrict__ bkf,
    const _Float16* __restrict__ wv,  const float* __restrict__ bv,
    _Float16* __restrict__ q_out, _Float16* __restrict__ kl_out,
    _Float16* __restrict__ kf_out, short* __restrict__ v_out) {
  const int tid  = threadIdx.x;
  const int w    = tid >> 6;
  const int lane = tid & 63;
  const int quad = lane >> 4;
  const int l15  = lane & 15;
  const int pass = blockIdx.x >> 8;
  const int bb   = blockIdx.x & 255;
  const int b    = bb >> 6;
  const int hwt  = (bb & 63) << 6;
  const int hw   = hwt + w * 16 + l15;

  const float* X = (pass == 0) ? cur : ((pass == 1) ? last : fut);
  const float* xp = X + (size_t)b * CIN * HWN + hw;

  float xbuf[2][8];
#pragma unroll
  for (int j = 0; j < 8; ++j) xbuf[0][j] = xp[(quad * 8 + j) * HWN];

  if (pass == 0) {
    f32x4 aq[4] = {}; f32x4 av[4] = {};
#pragma unroll
    for (int k0 = 0; k0 < CIN; k0 += 32) {
      int pi = (k0 >> 5) & 1;
      if (k0 + 32 < CIN)
#pragma unroll
        for (int j = 0; j < 8; ++j)
          xbuf[pi ^ 1][j] = xp[(k0 + 32 + quad * 8 + j) * HWN];
      f16x8 bh;
#pragma unroll
      for (int j = 0; j < 8; ++j) bh[j] = (_Float16)xbuf[pi][j];
#pragma unroll
      for (int mt = 0; mt < 4; ++mt) {
        f16x8 wa = *(const f16x8*)(wqk + (mt * 16 + l15) * CIN + k0 + quad * 8);
        aq[mt] = __builtin_amdgcn_mfma_f32_16x16x32_f16(wa, bh, aq[mt], 0, 0, 0);
        f16x8 wb = *(const f16x8*)(wv + (mt * 16 + l15) * CIN + k0 + quad * 8);
        av[mt] = __builtin_amdgcn_mfma_f32_16x16x32_f16(wb, bh, av[mt], 0, 0, 0);
      }
    }
#pragma unroll
    for (int mt = 0; mt < 4; ++mt)
#pragma unroll
      for (int r = 0; r < 4; ++r) {
        int oc = mt * 16 + quad * 4 + r;
        q_out[(b * CQ + oc) * HWN + hw] = (_Float16)(aq[mt][r] + bqk[oc] * LOG2E);
        v_out[(b * CQ + oc) * HWN + hw] = f2bf(av[mt][r] + bv[oc]);
      }
  } else {
    const _Float16* W = (pass == 1) ? wkl : wkf;
    const float* BI = (pass == 1) ? bkl : bkf;
    _Float16* OUT = (pass == 1) ? kl_out : kf_out;
    f32x4 a[4] = {};
#pragma unroll
    for (int k0 = 0; k0 < CIN; k0 += 32) {
      int pi = (k0 >> 5) & 1;
      if (k0 + 32 < CIN)
#pragma unroll
        for (int j = 0; j < 8; ++j)
          xbuf[pi ^ 1][j] = xp[(k0 + 32 + quad * 8 + j) * HWN];
      f16x8 bh;
#pragma unroll
      for (int j = 0; j < 8; ++j) bh[j] = (_Float16)xbuf[pi][j];
#pragma unroll
      for (int mt = 0; mt < 4; ++mt) {
        f16x8 wa = *(const f16x8*)(W + (mt * 16 + l15) * CIN + k0 + quad * 8);
        a[mt] = __builtin_amdgcn_mfma_f32_16x16x32_f16(wa, bh, a[mt], 0, 0, 0);
      }
    }
#pragma unroll
    for (int mt = 0; mt < 4; ++mt)
#pragma unroll
      for (int r = 0; r < 4; ++r) {
        int oc = mt * 16 + quad * 4 + r;
        OUT[(b * HWN + hw) * CQ + oc] = (_Float16)(a[mt][r] + BI[oc]);
      }
  }
}

// ---------------------------------------------------------------- attn ----
// R6 dataflow, rolled: S transposed (A=K,B=Q) -> exp in regs -> ds_write_b64
// into SINGLE P buffer (reads of P(t-1) are issued before writes of P(t);
// per-wave LDS ordering makes this safe) -> ds_read_b128 A-frags -> K=32
// bf16 PV. K and V register-double-buffered (V at ~1 full body distance).
// Loop is FORCIBLY rolled (#pragma unroll 1) to stay inside I-cache.
__global__ __launch_bounds__(256) void attn_kernel(
    const _Float16* __restrict__ qbuf, const _Float16* __restrict__ klbuf,
    const _Float16* __restrict__ kfbuf, const short* __restrict__ vbuf,
    _Float16* __restrict__ fused) {
  const int tid  = threadIdx.x;
  const int kh   = tid >> 6;                // key quarter
  const int lane = tid & 63;
  const int quad = lane >> 4;
  const int l15  = lane & 15;
  const int bx   = blockIdx.x;
  const int pair = bx & 1;
  const int b    = (bx >> 1) & 3;
  const int qt   = (bx >> 3) << 5;          // 32 queries per block

  const _Float16* K = (pair ? kfbuf : klbuf) + b * HWN * CQ;  // [key][c] f16
  const short*    V = vbuf + b * CQ * HWN;                     // [c][key] bf16

  // P: [wave][i][q=16][72] shorts = 18432 B. Combine buf [3][64][34] f32 =
  // 26112 B, aliased after a barrier.
  __shared__ __align__(16) char smem[26112];
  auto Plds = reinterpret_cast<short (*)[2][16][72]>(smem);
  auto Cbuf = reinterpret_cast<float (*)[64][34]>(smem);

  f16x8 qfrag[2][2];
#pragma unroll
  for (int i = 0; i < 2; ++i)
#pragma unroll
    for (int kk = 0; kk < 2; ++kk)
#pragma unroll
      for (int j = 0; j < 8; ++j)
        qfrag[i][kk][j] = qbuf[(b * CQ + kk * 32 + quad * 8 + j) * HWN + qt + i * 16 + l15];

  f32x4 Oacc[2][4] = {};       // [i][ct]: row=q(quad*4+r), col=c4(ct*16+l15)
  float psum[2] = {0.f, 0.f};  // per-lane partials (q=l15, this quad's keys)

  const int kt0 = kh << 10;    // 16 tiles of 64 keys

  f16x8  kF[2][4][2];          // K tile double buffer (tile t -> kF[t&1])
  bf16x8 vF[2][4][2];          // V tile double buffer (tile t -> vF[t&1])

  auto loadK = [&](int p, int t) {
    const _Float16* kp = K + (kt0 + t * 64) * CQ;
#pragma unroll
    for (int nt = 0; nt < 4; ++nt)
#pragma unroll
      for (int kk = 0; kk < 2; ++kk)
        kF[p][nt][kk] = *(const f16x8*)(kp + (nt * 16 + l15) * CQ + kk * 32 + quad * 8);
  };
  auto loadV = [&](int p, int t) {
#pragma unroll
    for (int ct = 0; ct < 4; ++ct)
#pragma unroll
      for (int kk = 0; kk < 2; ++kk)
        vF[p][ct][kk] = *(const bf16x8*)(V + (ct * 16 + l15) * HWN + kt0 + t * 64 + kk * 32 + quad * 8);
  };
  auto computeS = [&](int p, f32x4 (&ST)[2][4]) {
#pragma unroll
    for (int i = 0; i < 2; ++i)
#pragma unroll
      for (int nt = 0; nt < 4; ++nt)
#pragma unroll
        for (int kk = 0; kk < 2; ++kk)
          ST[i][nt] = __builtin_amdgcn_mfma_f32_16x16x32_f16(kF[p][nt][kk], qfrag[i][kk], ST[i][nt], 0, 0, 0);
  };
  auto readP = [&](bf16x8 (&pf)[2][2]) {
#pragma unroll
    for (int i = 0; i < 2; ++i)
#pragma unroll
      for (int kk = 0; kk < 2; ++kk)
        pf[i][kk] = *(const bf16x8*)&Plds[kh][i][l15][kk * 32 + quad * 8];  // b128
  };
  auto pvMFMA = [&](bf16x8 (&pf)[2][2], int vp) {
#pragma unroll
    for (int i = 0; i < 2; ++i)
#pragma unroll
      for (int kk = 0; kk < 2; ++kk)
#pragma unroll
        for (int ct = 0; ct < 4; ++ct)
          Oacc[i][ct] = __builtin_amdgcn_mfma_f32_16x16x32_bf16(pf[i][kk], vF[vp][ct][kk], Oacc[i][ct], 0, 0, 0);
  };
  auto expWrite = [&](f32x4 (&ST)[2][4]) {
#pragma unroll
    for (int i = 0; i < 2; ++i)
#pragma unroll
      for (int nt = 0; nt < 4; ++nt) {
        bf16x4 pw;
#pragma unroll
        for (int r = 0; r < 4; ++r) {
          float p = __builtin_amdgcn_exp2f(ST[i][nt][r] - C2OFF);
          uint32_t u = __float_as_uint(p) & 0xffff0000u;   // truncate to bf16
          psum[i] += __uint_as_float(u);                   // consistent with P
          pw[r] = (short)(u >> 16);
        }
        *(bf16x4*)&Plds[kh][i][l15][nt * 16 + quad * 4] = pw;  // b64
      }
  };

  f32x4 ST[2][4];

  // ---- prologue: bodies t=0,1 ----
  loadK(0, 0); loadK(1, 1); loadV(0, 0);
#pragma unroll
  for (int z = 0; z < 2; ++z) for (int y = 0; y < 4; ++y) ST[z][y] = f32x4{};
  computeS(0, ST); expWrite(ST);                        // P(0)
  {
    loadV(1, 1); loadK(0, 2);
    f32x4 ST1[2][4] = {};
    computeS(1, ST1);
    bf16x8 pf[2][2]; readP(pf);                         // P(0)
    pvMFMA(pf, 0);                                      // PV(0), V(0)
    expWrite(ST1);                                      // P(1)
  }

  // ---- steady state: bodies t=2..15, rolled ----
#pragma unroll 1
  for (int tt = 2; tt < 16; tt += 2) {
    {                                                   // t = tt (even, kF0)
      loadV(0, tt);
      if (tt + 1 < 16) loadK(1, tt + 1);
      f32x4 STl[2][4] = {};
      computeS(0, STl);
      bf16x8 pf[2][2]; readP(pf);                       // P(tt-1)
      pvMFMA(pf, 1);                                    // V(tt-1) in vF1
      expWrite(STl);                                    // P(tt)
    }
    {                                                   // t = tt+1 (odd, kF1)
      loadV(1, tt + 1);
      if (tt + 2 < 16) loadK(0, tt + 2);
      f32x4 STl[2][4] = {};
      computeS(1, STl);
      bf16x8 pf[2][2]; readP(pf);                       // P(tt)
      pvMFMA(pf, 0);                                    // V(tt) in vF0
      expWrite(STl);                                    // P(tt+1)
    }
  }
  // ---- epilogue: PV(15) ----
  {
    bf16x8 pf[2][2]; readP(pf);                         // P(15)
    pvMFMA(pf, 1);                                      // V(15) in vF1
  }

  // psum: reduce across quads -> every lane holds full row-sum for q=l15.
#pragma unroll
  for (int i = 0; i < 2; ++i) {
    psum[i] += __shfl_xor(psum[i], 16);
    psum[i] += __shfl_xor(psum[i], 32);
  }

  __syncthreads();   // all Plds traffic done before Cbuf overwrites smem
  if (kh > 0) {
    float* dst = Cbuf[kh - 1][lane];
#pragma unroll
    for (int i = 0; i < 2; ++i)
#pragma unroll
      for (int ct = 0; ct < 4; ++ct)
#pragma unroll
        for (int r = 0; r < 4; ++r) dst[i * 16 + ct * 4 + r] = Oacc[i][ct][r];
    dst[32] = psum[0]; dst[33] = psum[1];
  }
  __syncthreads();
  if (kh == 0) {
    float ltot[2] = {psum[0], psum[1]};
#pragma unroll
    for (int k = 0; k < 3; ++k) {
      const float* src = Cbuf[k][lane];
#pragma unroll
      for (int i = 0; i < 2; ++i)
#pragma unroll
        for (int ct = 0; ct < 4; ++ct)
#pragma unroll
          for (int r = 0; r < 4; ++r) Oacc[i][ct][r] += src[i * 16 + ct * 4 + r];
      ltot[0] += src[32]; ltot[1] += src[33];
    }
#pragma unroll
    for (int i = 0; i < 2; ++i)
#pragma unroll
      for (int r = 0; r < 4; ++r) {
        float lt = __shfl(ltot[i], quad * 4 + r);   // row-sum lives at lane q
        float invl = __builtin_amdgcn_rcpf(lt);
        int qi = qt + i * 16 + quad * 4 + r;
#pragma unroll
        for (int ct = 0; ct < 4; ++ct)
          fused[(b * HWN + qi) * 128 + pair * 64 + ct * 16 + l15] =
              (_Float16)(Oacc[i][ct][r] * invl);
      }
  }
}

// ---------------------------------------------------------------- fire ----
// (unchanged from R6) Wave = 16 hw x 64 oc; grid 1024.
__global__ __launch_bounds__(256) void fire_kernel(
    const _Float16* __restrict__ fused, const _Float16* __restrict__ wf,
    const float* __restrict__ scale, const float* __restrict__ shift,
    const float* __restrict__ cur, float* __restrict__ out) {
  const int tid  = threadIdx.x;
  const int w    = tid >> 6;
  const int lane = tid & 63;
  const int quad = lane >> 4;
  const int l15  = lane & 15;
  const int g    = blockIdx.x & 3;
  const int bb   = blockIdx.x >> 2;
  const int b    = bb >> 6;
  const int hwt  = (bb & 63) << 6;
  const int hwb  = hwt + w * 16;

  float curv[4][4];
#pragma unroll
  for (int mt = 0; mt < 4; ++mt)
#pragma unroll
    for (int r = 0; r < 4; ++r)
      curv[mt][r] = cur[(b * CIN + g * 64 + mt * 16 + quad * 4 + r) * HWN + hwb + l15];

  f16x8 bfr[4];
#pragma unroll
  for (int k0 = 0; k0 < 4; ++k0)
    bfr[k0] = *(const f16x8*)(fused + (b * HWN + hwb + l15) * 128 + k0 * 32 + quad * 8);

  f32x4 acc[4] = {};
#pragma unroll
  for (int k0 = 0; k0 < 4; ++k0)
#pragma unroll
    for (int mt = 0; mt < 4; ++mt) {
      f16x8 af = *(const f16x8*)(wf + (g * 64 + mt * 16 + l15) * 128 + k0 * 32 + quad * 8);
      acc[mt] = __builtin_amdgcn_mfma_f32_16x16x32_f16(af, bfr[k0], acc[mt], 0, 0, 0);
    }

#pragma unroll
  for (int mt = 0; mt < 4; ++mt)
#pragma unroll
    for (int r = 0; r < 4; ++r) {
      int oc = g * 64 + mt * 16 + quad * 4 + r;
      int idx = (b * CIN + oc) * HWN + hwb + l15;
      float y = curv[mt][r] + acc[mt][r] * scale[oc] + shift[oc];
      out[idx] = fmaxf(y, 0.f);
    }
}

// -------------------------------------------------------------- launch ----
extern "C" void kernel_launch(void* const* d_in, const int* in_sizes, int n_in,
                              void* d_out, int out_size, void* d_ws, size_t ws_size,
                              hipStream_t stream) {
  const float* last  = (const float*)d_in[0];
  const float* cur   = (const float*)d_in[1];
  const float* fut   = (const float*)d_in[2];
  const float* Wqk   = (const float*)d_in[3];
  const float* bqk   = (const float*)d_in[4];
  const float* Wkl   = (const float*)d_in[5];
  const float* bkl   = (const float*)d_in[6];
  const float* Wkf   = (const float*)d_in[7];
  const float* bkf   = (const float*)d_in[8];
  const float* Wv    = (const float*)d_in[9];
  const float* bv    = (const float*)d_in[10];
  const float* Wfire = (const float*)d_in[11];
  const float* bfire = (const float*)d_in[12];
  const float* gamma = (const float*)d_in[13];
  const float* beta  = (const float*)d_in[14];
  const float* mean  = (const float*)d_in[15];
  const float* var   = (const float*)d_in[16];

  char* ws = (char*)d_ws;
  _Float16* qb     = (_Float16*)(ws);                    // [4][64][4096]  2 MB
  _Float16* klb    = (_Float16*)(ws + (2u << 20));       // [4][4096][64]  2 MB
  _Float16* kfb    = (_Float16*)(ws + (4u << 20));       // [4][4096][64]  2 MB
  short*    vb     = (short*)   (ws + (6u << 20));       // [4][64][4096]  2 MB bf16
  _Float16* fusedb = (_Float16*)(ws + (8u << 20));       // [4][4096][128] 4 MB
  char* wsm = ws + (12u << 20);
  _Float16* wqk_h = (_Float16*)(wsm);
  _Float16* wkl_h = (_Float16*)(wsm + (32u << 10));
  _Float16* wkf_h = (_Float16*)(wsm + (64u << 10));
  _Float16* wv_h  = (_Float16*)(wsm + (96u << 10));
  _Float16* wf_h  = (_Float16*)(wsm + (128u << 10));
  float*    scale = (float*)   (wsm + (192u << 10));
  float*    shift = (float*)   (wsm + (193u << 10));
  float*    out   = (float*)d_out;

  prep_kernel<<<128, 256, 0, stream>>>(Wqk, Wkl, Wkf, Wv, Wfire, bfire,
                                       gamma, beta, mean, var,
                                       wqk_h, wkl_h, wkf_h, wv_h, wf_h, scale, shift);
  proj_kernel<<<768, 256, 0, stream>>>(cur, last, fut, wqk_h, bqk, wkl_h, bkl,
                                       wkf_h, bkf, wv_h, bv, qb, klb, kfb, vb);
  attn_kernel<<<1024, 256, 0, stream>>>(qb, klb, kfb, vb, fusedb);
  fire_kernel<<<1024, 256, 0, stream>>>(fusedb, wf_h, scale, shift, cur, out);
}

// Round 8
// 232.363 us; speedup vs baseline: 1.1743x; 1.1743x over previous
//
#include <hip/hip_runtime.h>
#include <math.h>
#include <stdint.h>

// B=4, C=256, H=W=64 -> HW=4096, C4=64
#define HWN 4096
#define CIN 256
#define CQ 64
#define LOG2E 1.44269504f
#define C2OFF 56.0f    // fixed softmax offset (exp2 domain); P kept in bf16
                       // (fp32 exponent range) -> tail-query underflow impossible

typedef __attribute__((ext_vector_type(8))) _Float16 f16x8;
typedef __attribute__((ext_vector_type(8))) short    bf16x8;
typedef __attribute__((ext_vector_type(4))) short    bf16x4;
typedef __attribute__((ext_vector_type(4))) float    f32x4;

__device__ __forceinline__ short f2bf(float f) {
  union { float f; uint32_t u; } c; c.f = f;
  uint32_t r = (c.u + 0x7FFFu + ((c.u >> 16) & 1u)) >> 16;   // RNE
  return (short)(uint16_t)r;
}

// async global->LDS, 16B per lane; LDS dest = wave-uniform base + lane*16.
__device__ __forceinline__ void stage16(const void* g, void* l) {
  __builtin_amdgcn_global_load_lds(
      (const __attribute__((address_space(1))) uint32_t*)g,
      (__attribute__((address_space(3))) uint32_t*)l, 16, 0, 0);
}

// ---------------------------------------------------------------- prep ----
__global__ __launch_bounds__(256) void prep_kernel(
    const float* __restrict__ Wqk, const float* __restrict__ Wkl,
    const float* __restrict__ Wkf, const float* __restrict__ Wv,
    const float* __restrict__ Wfire, const float* __restrict__ bfire,
    const float* __restrict__ gamma, const float* __restrict__ beta,
    const float* __restrict__ mean,  const float* __restrict__ var,
    _Float16* __restrict__ wqk_h, _Float16* __restrict__ wkl_h,
    _Float16* __restrict__ wkf_h, _Float16* __restrict__ wv_h,
    _Float16* __restrict__ wf_h, float* __restrict__ scale, float* __restrict__ shift) {
  int gid = blockIdx.x * 256 + threadIdx.x;
  if (gid < CQ * CIN) {
    wqk_h[gid] = (_Float16)(Wqk[gid] * LOG2E);
    wkl_h[gid] = (_Float16)Wkl[gid];
    wkf_h[gid] = (_Float16)Wkf[gid];
    wv_h[gid]  = (_Float16)Wv[gid];
  }
  if (gid < CIN * 128) wf_h[gid] = (_Float16)Wfire[gid];
  if (gid < CIN) {
    float inv = gamma[gid] / sqrtf(var[gid] + 1e-5f);
    scale[gid] = inv;
    shift[gid] = (bfire[gid] - mean[gid]) * inv + beta[gid];
  }
}

// ---------------------------------------------------------------- proj ----
// (unchanged from R6) 3 passes: cur->q+v; last->kl; fut->kf. Grid 768.
__global__ __launch_bounds__(256) void proj_kernel(
    const float* __restrict__ cur, const float* __restrict__ last, const float* __restrict__ fut,
    const _Float16* __restrict__ wqk, const float* __restrict__ bqk,
    const _Float16* __restrict__ wkl, const float* __restrict__ bkl,
    const _Float16* __restrict__ wkf, const float* __restrict__ bkf,
    const _Float16* __restrict__ wv,  const float* __restrict__ bv,
    _Float16* __restrict__ q_out, _Float16* __restrict__ kl_out,
    _Float16* __restrict__ kf_out, short* __restrict__ v_out) {
  const int tid  = threadIdx.x;
  const int w    = tid >> 6;
  const int lane = tid & 63;
  const int quad = lane >> 4;
  const int l15  = lane & 15;
  const int pass = blockIdx.x >> 8;
  const int bb   = blockIdx.x & 255;
  const int b    = bb >> 6;
  const int hwt  = (bb & 63) << 6;
  const int hw   = hwt + w * 16 + l15;

  const float* X = (pass == 0) ? cur : ((pass == 1) ? last : fut);
  const float* xp = X + (size_t)b * CIN * HWN + hw;

  float xbuf[2][8];
#pragma unroll
  for (int j = 0; j < 8; ++j) xbuf[0][j] = xp[(quad * 8 + j) * HWN];

  if (pass == 0) {
    f32x4 aq[4] = {}; f32x4 av[4] = {};
#pragma unroll
    for (int k0 = 0; k0 < CIN; k0 += 32) {
      int pi = (k0 >> 5) & 1;
      if (k0 + 32 < CIN)
#pragma unroll
        for (int j = 0; j < 8; ++j)
          xbuf[pi ^ 1][j] = xp[(k0 + 32 + quad * 8 + j) * HWN];
      f16x8 bh;
#pragma unroll
      for (int j = 0; j < 8; ++j) bh[j] = (_Float16)xbuf[pi][j];
#pragma unroll
      for (int mt = 0; mt < 4; ++mt) {
        f16x8 wa = *(const f16x8*)(wqk + (mt * 16 + l15) * CIN + k0 + quad * 8);
        aq[mt] = __builtin_amdgcn_mfma_f32_16x16x32_f16(wa, bh, aq[mt], 0, 0, 0);
        f16x8 wb = *(const f16x8*)(wv + (mt * 16 + l15) * CIN + k0 + quad * 8);
        av[mt] = __builtin_amdgcn_mfma_f32_16x16x32_f16(wb, bh, av[mt], 0, 0, 0);
      }
    }
#pragma unroll
    for (int mt = 0; mt < 4; ++mt)
#pragma unroll
      for (int r = 0; r < 4; ++r) {
        int oc = mt * 16 + quad * 4 + r;
        q_out[(b * CQ + oc) * HWN + hw] = (_Float16)(aq[mt][r] + bqk[oc] * LOG2E);
        v_out[(b * CQ + oc) * HWN + hw] = f2bf(av[mt][r] + bv[oc]);
      }
  } else {
    const _Float16* W = (pass == 1) ? wkl : wkf;
    const float* BI = (pass == 1) ? bkl : bkf;
    _Float16* OUT = (pass == 1) ? kl_out : kf_out;
    f32x4 a[4] = {};
#pragma unroll
    for (int k0 = 0; k0 < CIN; k0 += 32) {
      int pi = (k0 >> 5) & 1;
      if (k0 + 32 < CIN)
#pragma unroll
        for (int j = 0; j < 8; ++j)
          xbuf[pi ^ 1][j] = xp[(k0 + 32 + quad * 8 + j) * HWN];
      f16x8 bh;
#pragma unroll
      for (int j = 0; j < 8; ++j) bh[j] = (_Float16)xbuf[pi][j];
#pragma unroll
      for (int mt = 0; mt < 4; ++mt) {
        f16x8 wa = *(const f16x8*)(W + (mt * 16 + l15) * CIN + k0 + quad * 8);
        a[mt] = __builtin_amdgcn_mfma_f32_16x16x32_f16(wa, bh, a[mt], 0, 0, 0);
      }
    }
#pragma unroll
    for (int mt = 0; mt < 4; ++mt)
#pragma unroll
      for (int r = 0; r < 4; ++r) {
        int oc = mt * 16 + quad * 4 + r;
        OUT[(b * HWN + hw) * CQ + oc] = (_Float16)(a[mt][r] + BI[oc]);
      }
  }
}

// ---------------------------------------------------------------- attn ----
// Block = 128 queries (4 waves x 32q) x ALL 4096 keys (64 bodies). K/V tiles
// staged to LDS via async global_load_lds (width 16, zero VGPR), double-
// buffered, shared by all 4 waves. One barrier per body (m97 pattern).
// S transposed (A=K,B=Q) -> exp in regs -> b64 P write -> b128 P read ->
// K=32 bf16 PV. bx&7 = (pair,b) -> XCD-local L2 working set (1 MB).
// Grid 256 (1 block/CU). launch_bounds(256,1): no VGPR-pressure load sinking.
__global__ __launch_bounds__(256, 1) void attn_kernel(
    const _Float16* __restrict__ qbuf, const _Float16* __restrict__ klbuf,
    const _Float16* __restrict__ kfbuf, const short* __restrict__ vbuf,
    _Float16* __restrict__ fused) {
  const int tid  = threadIdx.x;
  const int w    = tid >> 6;
  const int lane = tid & 63;
  const int quad = lane >> 4;
  const int l15  = lane & 15;
  const int bx   = blockIdx.x;
  const int pair = bx & 1;
  const int b    = (bx >> 1) & 3;
  const int qt   = (bx >> 3) << 7;          // 128 queries per block

  const _Float16* K  = (pair ? kfbuf : klbuf) + (size_t)b * HWN * CQ;  // [key][c]
  const short*    Vg = vbuf + (size_t)b * CQ * HWN;                    // [c][key]

  __shared__ __align__(16) _Float16 Kt[2][64][64];   // [buf][key][c]   16 KB
  __shared__ __align__(16) short    Vt[2][64][64];   // [buf][c][key]   16 KB
  __shared__ __align__(16) short    Pl[4][2][16][72];//                 18 KB

  const int qbase = qt + w * 32;
  f16x8 qfrag[2][2];
#pragma unroll
  for (int i = 0; i < 2; ++i)
#pragma unroll
    for (int kk = 0; kk < 2; ++kk)
#pragma unroll
      for (int j = 0; j < 8; ++j)
        qfrag[i][kk][j] = qbuf[(b * CQ + kk * 32 + quad * 8 + j) * HWN + qbase + i * 16 + l15];

  f32x4 Oacc[2][4] = {};       // [i][ct]: row=q(quad*4+r), col=c4(ct*16+l15)
  float psum[2] = {0.f, 0.f};  // per-lane partials (q=l15, this quad's keys)

  // Wave w stages rows [w*16, w*16+16) of each 64-row tile, 2 rounds x 8 rows.
  auto stageK = [&](int buf, int t) {
    const _Float16* g0 = K + (size_t)(t * 64 + w * 16) * CQ + (lane >> 3) * CQ + (lane & 7) * 8;
#pragma unroll
    for (int r = 0; r < 2; ++r)
      stage16(g0 + r * 8 * CQ, &Kt[buf][w * 16 + r * 8][0]);
  };
  auto stageV = [&](int buf, int t) {
    const short* g0 = Vg + (size_t)(w * 16 + (lane >> 3)) * HWN + t * 64 + (lane & 7) * 8;
#pragma unroll
    for (int r = 0; r < 2; ++r)
      stage16(g0 + r * 8 * HWN, &Vt[buf][w * 16 + r * 8][0]);
  };

  auto body = [&](int buf) {
    f16x8 kf[4][2];
#pragma unroll
    for (int nt = 0; nt < 4; ++nt)
#pragma unroll
      for (int kk = 0; kk < 2; ++kk)
        kf[nt][kk] = *(const f16x8*)&Kt[buf][nt * 16 + l15][kk * 32 + quad * 8];
    bf16x8 vf[4][2];
#pragma unroll
    for (int ct = 0; ct < 4; ++ct)
#pragma unroll
      for (int kk = 0; kk < 2; ++kk)
        vf[ct][kk] = *(const bf16x8*)&Vt[buf][ct * 16 + l15][kk * 32 + quad * 8];
    f32x4 ST[2][4] = {};
#pragma unroll
    for (int i = 0; i < 2; ++i)
#pragma unroll
      for (int nt = 0; nt < 4; ++nt)
#pragma unroll
        for (int kk = 0; kk < 2; ++kk)
          ST[i][nt] = __builtin_amdgcn_mfma_f32_16x16x32_f16(kf[nt][kk], qfrag[i][kk], ST[i][nt], 0, 0, 0);
#pragma unroll
    for (int i = 0; i < 2; ++i)
#pragma unroll
      for (int nt = 0; nt < 4; ++nt) {
        bf16x4 pw;
#pragma unroll
        for (int r = 0; r < 4; ++r) {
          float p = __builtin_amdgcn_exp2f(ST[i][nt][r] - C2OFF);
          uint32_t u = __float_as_uint(p) & 0xffff0000u;   // truncate to bf16
          psum[i] += __uint_as_float(u);                   // consistent with P
          pw[r] = (short)(u >> 16);
        }
        *(bf16x4*)&Pl[w][i][l15][nt * 16 + quad * 4] = pw; // b64
      }
#pragma unroll
    for (int i = 0; i < 2; ++i)
#pragma unroll
      for (int kk = 0; kk < 2; ++kk) {
        bf16x8 pf = *(const bf16x8*)&Pl[w][i][l15][kk * 32 + quad * 8];  // b128
#pragma unroll
        for (int ct = 0; ct < 4; ++ct)
          Oacc[i][ct] = __builtin_amdgcn_mfma_f32_16x16x32_bf16(pf, vf[ct][kk], Oacc[i][ct], 0, 0, 0);
      }
  };

  stageK(0, 0); stageV(0, 0);
  __syncthreads();
#pragma unroll 1
  for (int tt = 0; tt < 64; tt += 2) {
    stageK(1, tt + 1); stageV(1, tt + 1);     // tt+1 <= 63 always
    body(0);
    __syncthreads();                           // drains staging of tt+1
    if (tt + 2 < 64) { stageK(0, tt + 2); stageV(0, tt + 2); }
    body(1);
    __syncthreads();
  }

  // psum: reduce across quads -> every lane holds full row-sum for q=l15.
#pragma unroll
  for (int i = 0; i < 2; ++i) {
    psum[i] += __shfl_xor(psum[i], 16);
    psum[i] += __shfl_xor(psum[i], 32);
  }

  // epilogue: each wave owns its 32 queries outright — direct store.
#pragma unroll
  for (int i = 0; i < 2; ++i)
#pragma unroll
    for (int r = 0; r < 4; ++r) {
      float lt = __shfl(psum[i], quad * 4 + r);   // row-sum lives at lane q
      float invl = __builtin_amdgcn_rcpf(lt);
      int qi = qbase + i * 16 + quad * 4 + r;
#pragma unroll
      for (int ct = 0; ct < 4; ++ct)
        fused[((size_t)b * HWN + qi) * 128 + pair * 64 + ct * 16 + l15] =
            (_Float16)(Oacc[i][ct][r] * invl);
    }
}

// ---------------------------------------------------------------- fire ----
// (unchanged from R6) Wave = 16 hw x 64 oc; grid 1024.
__global__ __launch_bounds__(256) void fire_kernel(
    const _Float16* __restrict__ fused, const _Float16* __restrict__ wf,
    const float* __restrict__ scale, const float* __restrict__ shift,
    const float* __restrict__ cur, float* __restrict__ out) {
  const int tid  = threadIdx.x;
  const int w    = tid >> 6;
  const int lane = tid & 63;
  const int quad = lane >> 4;
  const int l15  = lane & 15;
  const int g    = blockIdx.x & 3;
  const int bb   = blockIdx.x >> 2;
  const int b    = bb >> 6;
  const int hwt  = (bb & 63) << 6;
  const int hwb  = hwt + w * 16;

  float curv[4][4];
#pragma unroll
  for (int mt = 0; mt < 4; ++mt)
#pragma unroll
    for (int r = 0; r < 4; ++r)
      curv[mt][r] = cur[(b * CIN + g * 64 + mt * 16 + quad * 4 + r) * HWN + hwb + l15];

  f16x8 bfr[4];
#pragma unroll
  for (int k0 = 0; k0 < 4; ++k0)
    bfr[k0] = *(const f16x8*)(fused + ((size_t)b * HWN + hwb + l15) * 128 + k0 * 32 + quad * 8);

  f32x4 acc[4] = {};
#pragma unroll
  for (int k0 = 0; k0 < 4; ++k0)
#pragma unroll
    for (int mt = 0; mt < 4; ++mt) {
      f16x8 af = *(const f16x8*)(wf + (g * 64 + mt * 16 + l15) * 128 + k0 * 32 + quad * 8);
      acc[mt] = __builtin_amdgcn_mfma_f32_16x16x32_f16(af, bfr[k0], acc[mt], 0, 0, 0);
    }

#pragma unroll
  for (int mt = 0; mt < 4; ++mt)
#pragma unroll
    for (int r = 0; r < 4; ++r) {
      int oc = g * 64 + mt * 16 + quad * 4 + r;
      int idx = (b * CIN + oc) * HWN + hwb + l15;
      float y = curv[mt][r] + acc[mt][r] * scale[oc] + shift[oc];
      out[idx] = fmaxf(y, 0.f);
    }
}

// -------------------------------------------------------------- launch ----
extern "C" void kernel_launch(void* const* d_in, const int* in_sizes, int n_in,
                              void* d_out, int out_size, void* d_ws, size_t ws_size,
                              hipStream_t stream) {
  const float* last  = (const float*)d_in[0];
  const float* cur   = (const float*)d_in[1];
  const float* fut   = (const float*)d_in[2];
  const float* Wqk   = (const float*)d_in[3];
  const float* bqk   = (const float*)d_in[4];
  const float* Wkl   = (const float*)d_in[5];
  const float* bkl   = (const float*)d_in[6];
  const float* Wkf   = (const float*)d_in[7];
  const float* bkf   = (const float*)d_in[8];
  const float* Wv    = (const float*)d_in[9];
  const float* bv    = (const float*)d_in[10];
  const float* Wfire = (const float*)d_in[11];
  const float* bfire = (const float*)d_in[12];
  const float* gamma = (const float*)d_in[13];
  const float* beta  = (const float*)d_in[14];
  const float* mean  = (const float*)d_in[15];
  const float* var   = (const float*)d_in[16];

  char* ws = (char*)d_ws;
  _Float16* qb     = (_Float16*)(ws);                    // [4][64][4096]  2 MB
  _Float16* klb    = (_Float16*)(ws + (2u << 20));       // [4][4096][64]  2 MB
  _Float16* kfb    = (_Float16*)(ws + (4u << 20));       // [4][4096][64]  2 MB
  short*    vb     = (short*)   (ws + (6u << 20));       // [4][64][4096]  2 MB bf16
  _Float16* fusedb = (_Float16*)(ws + (8u << 20));       // [4][4096][128] 4 MB
  char* wsm = ws + (12u << 20);
  _Float16* wqk_h = (_Float16*)(wsm);
  _Float16* wkl_h = (_Float16*)(wsm + (32u << 10));
  _Float16* wkf_h = (_Float16*)(wsm + (64u << 10));
  _Float16* wv_h  = (_Float16*)(wsm + (96u << 10));
  _Float16* wf_h  = (_Float16*)(wsm + (128u << 10));
  float*    scale = (float*)   (wsm + (192u << 10));
  float*    shift = (float*)   (wsm + (193u << 10));
  float*    out   = (float*)d_out;

  prep_kernel<<<128, 256, 0, stream>>>(Wqk, Wkl, Wkf, Wv, Wfire, bfire,
                                       gamma, beta, mean, var,
                                       wqk_h, wkl_h, wkf_h, wv_h, wf_h, scale, shift);
  proj_kernel<<<768, 256, 0, stream>>>(cur, last, fut, wqk_h, bqk, wkl_h, bkl,
                                       wkf_h, bkf, wv_h, bv, qb, klb, kfb, vb);
  attn_kernel<<<256, 256, 0, stream>>>(qb, klb, kfb, vb, fusedb);
  fire_kernel<<<1024, 256, 0, stream>>>(fusedb, wf_h, scale, shift, cur, out);
}

// Round 9
// 206.601 us; speedup vs baseline: 1.3207x; 1.1247x over previous
//
#include <hip/hip_runtime.h>
#include <math.h>
#include <stdint.h>

// B=4, C=256, H=W=64 -> HW=4096, C4=64
#define HWN 4096
#define CIN 256
#define CQ 64
#define LOG2E 1.44269504f
#define C2OFF 56.0f    // fixed softmax offset (exp2 domain); P kept in bf16
                       // (fp32 exponent range) -> tail-query underflow impossible

typedef __attribute__((ext_vector_type(8))) _Float16 f16x8;
typedef __attribute__((ext_vector_type(8))) short    bf16x8;
typedef __attribute__((ext_vector_type(4))) short    bf16x4;
typedef __attribute__((ext_vector_type(4))) float    f32x4;

__device__ __forceinline__ short f2bf(float f) {
  union { float f; uint32_t u; } c; c.f = f;
  uint32_t r = (c.u + 0x7FFFu + ((c.u >> 16) & 1u)) >> 16;   // RNE
  return (short)(uint16_t)r;
}

// async global->LDS, 16B per lane; LDS dest = wave-uniform base + lane*16.
__device__ __forceinline__ void stage16(const void* g, void* l) {
  __builtin_amdgcn_global_load_lds(
      (const __attribute__((address_space(1))) uint32_t*)g,
      (__attribute__((address_space(3))) uint32_t*)l, 16, 0, 0);
}

// ---------------------------------------------------------------- prep ----
__global__ __launch_bounds__(256) void prep_kernel(
    const float* __restrict__ Wqk, const float* __restrict__ Wkl,
    const float* __restrict__ Wkf, const float* __restrict__ Wv,
    const float* __restrict__ Wfire, const float* __restrict__ bfire,
    const float* __restrict__ gamma, const float* __restrict__ beta,
    const float* __restrict__ mean,  const float* __restrict__ var,
    _Float16* __restrict__ wqk_h, _Float16* __restrict__ wkl_h,
    _Float16* __restrict__ wkf_h, _Float16* __restrict__ wv_h,
    _Float16* __restrict__ wf_h, float* __restrict__ scale, float* __restrict__ shift) {
  int gid = blockIdx.x * 256 + threadIdx.x;
  if (gid < CQ * CIN) {
    wqk_h[gid] = (_Float16)(Wqk[gid] * LOG2E);
    wkl_h[gid] = (_Float16)Wkl[gid];
    wkf_h[gid] = (_Float16)Wkf[gid];
    wv_h[gid]  = (_Float16)Wv[gid];
  }
  if (gid < CIN * 128) wf_h[gid] = (_Float16)Wfire[gid];
  if (gid < CIN) {
    float inv = gamma[gid] / sqrtf(var[gid] + 1e-5f);
    scale[gid] = inv;
    shift[gid] = (bfire[gid] - mean[gid]) * inv + beta[gid];
  }
}

// ---------------------------------------------------------------- proj ----
// (unchanged from R8) 3 passes: cur->q+v; last->kl; fut->kf. Grid 768.
__global__ __launch_bounds__(256) void proj_kernel(
    const float* __restrict__ cur, const float* __restrict__ last, const float* __restrict__ fut,
    const _Float16* __restrict__ wqk, const float* __restrict__ bqk,
    const _Float16* __restrict__ wkl, const float* __restrict__ bkl,
    const _Float16* __restrict__ wkf, const float* __restrict__ bkf,
    const _Float16* __restrict__ wv,  const float* __restrict__ bv,
    _Float16* __restrict__ q_out, _Float16* __restrict__ kl_out,
    _Float16* __restrict__ kf_out, short* __restrict__ v_out) {
  const int tid  = threadIdx.x;
  const int w    = tid >> 6;
  const int lane = tid & 63;
  const int quad = lane >> 4;
  const int l15  = lane & 15;
  const int pass = blockIdx.x >> 8;
  const int bb   = blockIdx.x & 255;
  const int b    = bb >> 6;
  const int hwt  = (bb & 63) << 6;
  const int hw   = hwt + w * 16 + l15;

  const float* X = (pass == 0) ? cur : ((pass == 1) ? last : fut);
  const float* xp = X + (size_t)b * CIN * HWN + hw;

  float xbuf[2][8];
#pragma unroll
  for (int j = 0; j < 8; ++j) xbuf[0][j] = xp[(quad * 8 + j) * HWN];

  if (pass == 0) {
    f32x4 aq[4] = {}; f32x4 av[4] = {};
#pragma unroll
    for (int k0 = 0; k0 < CIN; k0 += 32) {
      int pi = (k0 >> 5) & 1;
      if (k0 + 32 < CIN)
#pragma unroll
        for (int j = 0; j < 8; ++j)
          xbuf[pi ^ 1][j] = xp[(k0 + 32 + quad * 8 + j) * HWN];
      f16x8 bh;
#pragma unroll
      for (int j = 0; j < 8; ++j) bh[j] = (_Float16)xbuf[pi][j];
#pragma unroll
      for (int mt = 0; mt < 4; ++mt) {
        f16x8 wa = *(const f16x8*)(wqk + (mt * 16 + l15) * CIN + k0 + quad * 8);
        aq[mt] = __builtin_amdgcn_mfma_f32_16x16x32_f16(wa, bh, aq[mt], 0, 0, 0);
        f16x8 wb = *(const f16x8*)(wv + (mt * 16 + l15) * CIN + k0 + quad * 8);
        av[mt] = __builtin_amdgcn_mfma_f32_16x16x32_f16(wb, bh, av[mt], 0, 0, 0);
      }
    }
#pragma unroll
    for (int mt = 0; mt < 4; ++mt)
#pragma unroll
      for (int r = 0; r < 4; ++r) {
        int oc = mt * 16 + quad * 4 + r;
        q_out[(b * CQ + oc) * HWN + hw] = (_Float16)(aq[mt][r] + bqk[oc] * LOG2E);
        v_out[(b * CQ + oc) * HWN + hw] = f2bf(av[mt][r] + bv[oc]);
      }
  } else {
    const _Float16* W = (pass == 1) ? wkl : wkf;
    const float* BI = (pass == 1) ? bkl : bkf;
    _Float16* OUT = (pass == 1) ? kl_out : kf_out;
    f32x4 a[4] = {};
#pragma unroll
    for (int k0 = 0; k0 < CIN; k0 += 32) {
      int pi = (k0 >> 5) & 1;
      if (k0 + 32 < CIN)
#pragma unroll
        for (int j = 0; j < 8; ++j)
          xbuf[pi ^ 1][j] = xp[(k0 + 32 + quad * 8 + j) * HWN];
      f16x8 bh;
#pragma unroll
      for (int j = 0; j < 8; ++j) bh[j] = (_Float16)xbuf[pi][j];
#pragma unroll
      for (int mt = 0; mt < 4; ++mt) {
        f16x8 wa = *(const f16x8*)(W + (mt * 16 + l15) * CIN + k0 + quad * 8);
        a[mt] = __builtin_amdgcn_mfma_f32_16x16x32_f16(wa, bh, a[mt], 0, 0, 0);
      }
    }
#pragma unroll
    for (int mt = 0; mt < 4; ++mt)
#pragma unroll
      for (int r = 0; r < 4; ++r) {
        int oc = mt * 16 + quad * 4 + r;
        OUT[(b * HWN + hw) * CQ + oc] = (_Float16)(a[mt][r] + BI[oc]);
      }
  }
}

// ---------------------------------------------------------------- attn ----
// R8 structure + two fixes:
//  (1) XOR-swizzled K/V tiles: logical 16B chunk c of row r stored at
//      physical chunk c^(r&7). Staging permutes each lane's GLOBAL source
//      chunk (LDS dest stays contiguous per global_load_lds rules); readers
//      XOR with l15&7 -> all ds_read_b128 spread over 32 banks (2-way = free).
//  (2) 64 q/block (4 waves x 16 q), grid 512 -> 2 blocks/CU, 2 waves/SIMD:
//      one block computes while the other drains its barrier (m114 overlap).
__global__ __launch_bounds__(256, 2) void attn_kernel(
    const _Float16* __restrict__ qbuf, const _Float16* __restrict__ klbuf,
    const _Float16* __restrict__ kfbuf, const short* __restrict__ vbuf,
    _Float16* __restrict__ fused) {
  const int tid  = threadIdx.x;
  const int w    = tid >> 6;
  const int lane = tid & 63;
  const int quad = lane >> 4;
  const int l15  = lane & 15;
  const int bx   = blockIdx.x;
  const int pair = bx & 1;
  const int b    = (bx >> 1) & 3;
  const int qt   = (bx >> 3) << 6;          // 64 queries per block

  const _Float16* K  = (pair ? kfbuf : klbuf) + (size_t)b * HWN * CQ;  // [key][c]
  const short*    Vg = vbuf + (size_t)b * CQ * HWN;                    // [c][key]

  __shared__ __align__(16) _Float16 Kt[2][64][64];   // [buf][key][c]   16 KB
  __shared__ __align__(16) short    Vt[2][64][64];   // [buf][c][key]   16 KB
  __shared__ __align__(16) short    Pl[4][16][72];   //                  9 KB

  const int qbase = qt + w * 16;
  f16x8 qfrag[2];
#pragma unroll
  for (int kk = 0; kk < 2; ++kk)
#pragma unroll
    for (int j = 0; j < 8; ++j)
      qfrag[kk][j] = qbuf[(b * CQ + kk * 32 + quad * 8 + j) * HWN + qbase + l15];

  f32x4 Oacc[4] = {};          // [ct]: row=q(quad*4+r), col=c4(ct*16+l15)
  float psum = 0.f;            // per-lane partial (q=l15, this quad's keys)

  const int swz = (lane & 7) ^ ((lane >> 3) & 7);    // staging source chunk
  const int rswz = l15 & 7;                          // reader XOR key

  // Wave w stages rows [w*16, w*16+16) of each 64-row tile, 2 x 8 rows.
  auto stageK = [&](int buf, int t) {
#pragma unroll
    for (int r = 0; r < 2; ++r)
      stage16(K + (size_t)(t * 64 + w * 16 + r * 8 + (lane >> 3)) * CQ + swz * 8,
              &Kt[buf][w * 16 + r * 8][0]);
  };
  auto stageV = [&](int buf, int t) {
#pragma unroll
    for (int r = 0; r < 2; ++r)
      stage16(Vg + (size_t)(w * 16 + r * 8 + (lane >> 3)) * HWN + t * 64 + swz * 8,
              &Vt[buf][w * 16 + r * 8][0]);
  };

  auto body = [&](int buf) {
    f16x8 kf[4][2];
#pragma unroll
    for (int nt = 0; nt < 4; ++nt)
#pragma unroll
      for (int kk = 0; kk < 2; ++kk)
        kf[nt][kk] = *(const f16x8*)&Kt[buf][nt * 16 + l15][((kk * 4 + quad) ^ rswz) * 8];
    bf16x8 vf[4][2];
#pragma unroll
    for (int ct = 0; ct < 4; ++ct)
#pragma unroll
      for (int kk = 0; kk < 2; ++kk)
        vf[ct][kk] = *(const bf16x8*)&Vt[buf][ct * 16 + l15][((kk * 4 + quad) ^ rswz) * 8];
    f32x4 ST[4] = {};
#pragma unroll
    for (int nt = 0; nt < 4; ++nt)
#pragma unroll
      for (int kk = 0; kk < 2; ++kk)
        ST[nt] = __builtin_amdgcn_mfma_f32_16x16x32_f16(kf[nt][kk], qfrag[kk], ST[nt], 0, 0, 0);
#pragma unroll
    for (int nt = 0; nt < 4; ++nt) {
      bf16x4 pw;
#pragma unroll
      for (int r = 0; r < 4; ++r) {
        float p = __builtin_amdgcn_exp2f(ST[nt][r] - C2OFF);
        uint32_t u = __float_as_uint(p) & 0xffff0000u;   // truncate to bf16
        psum += __uint_as_float(u);                      // consistent with P
        pw[r] = (short)(u >> 16);
      }
      *(bf16x4*)&Pl[w][l15][nt * 16 + quad * 4] = pw;    // b64
    }
#pragma unroll
    for (int kk = 0; kk < 2; ++kk) {
      bf16x8 pf = *(const bf16x8*)&Pl[w][l15][kk * 32 + quad * 8];  // b128
#pragma unroll
      for (int ct = 0; ct < 4; ++ct)
        Oacc[ct] = __builtin_amdgcn_mfma_f32_16x16x32_bf16(pf, vf[ct][kk], Oacc[ct], 0, 0, 0);
    }
  };

  stageK(0, 0); stageV(0, 0);
  __syncthreads();
#pragma unroll 1
  for (int tt = 0; tt < 64; tt += 2) {
    stageK(1, tt + 1); stageV(1, tt + 1);     // tt+1 <= 63 always
    body(0);
    __syncthreads();                           // drains staging of tt+1
    if (tt + 2 < 64) { stageK(0, tt + 2); stageV(0, tt + 2); }
    body(1);
    __syncthreads();
  }

  // psum: reduce across quads -> every lane holds full row-sum for q=l15.
  psum += __shfl_xor(psum, 16);
  psum += __shfl_xor(psum, 32);

  // epilogue: each wave owns its 16 queries outright — direct store.
#pragma unroll
  for (int r = 0; r < 4; ++r) {
    float lt = __shfl(psum, quad * 4 + r);     // row-sum lives at lane q
    float invl = __builtin_amdgcn_rcpf(lt);
    int qi = qbase + quad * 4 + r;
#pragma unroll
    for (int ct = 0; ct < 4; ++ct)
      fused[((size_t)b * HWN + qi) * 128 + pair * 64 + ct * 16 + l15] =
          (_Float16)(Oacc[ct][r] * invl);
  }
}

// ---------------------------------------------------------------- fire ----
// (unchanged from R8) Wave = 16 hw x 64 oc; grid 1024.
__global__ __launch_bounds__(256) void fire_kernel(
    const _Float16* __restrict__ fused, const _Float16* __restrict__ wf,
    const float* __restrict__ scale, const float* __restrict__ shift,
    const float* __restrict__ cur, float* __restrict__ out) {
  const int tid  = threadIdx.x;
  const int w    = tid >> 6;
  const int lane = tid & 63;
  const int quad = lane >> 4;
  const int l15  = lane & 15;
  const int g    = blockIdx.x & 3;
  const int bb   = blockIdx.x >> 2;
  const int b    = bb >> 6;
  const int hwt  = (bb & 63) << 6;
  const int hwb  = hwt + w * 16;

  float curv[4][4];
#pragma unroll
  for (int mt = 0; mt < 4; ++mt)
#pragma unroll
    for (int r = 0; r < 4; ++r)
      curv[mt][r] = cur[(b * CIN + g * 64 + mt * 16 + quad * 4 + r) * HWN + hwb + l15];

  f16x8 bfr[4];
#pragma unroll
  for (int k0 = 0; k0 < 4; ++k0)
    bfr[k0] = *(const f16x8*)(fused + ((size_t)b * HWN + hwb + l15) * 128 + k0 * 32 + quad * 8);

  f32x4 acc[4] = {};
#pragma unroll
  for (int k0 = 0; k0 < 4; ++k0)
#pragma unroll
    for (int mt = 0; mt < 4; ++mt) {
      f16x8 af = *(const f16x8*)(wf + (g * 64 + mt * 16 + l15) * 128 + k0 * 32 + quad * 8);
      acc[mt] = __builtin_amdgcn_mfma_f32_16x16x32_f16(af, bfr[k0], acc[mt], 0, 0, 0);
    }

#pragma unroll
  for (int mt = 0; mt < 4; ++mt)
#pragma unroll
    for (int r = 0; r < 4; ++r) {
      int oc = g * 64 + mt * 16 + quad * 4 + r;
      int idx = (b * CIN + oc) * HWN + hwb + l15;
      float y = curv[mt][r] + acc[mt][r] * scale[oc] + shift[oc];
      out[idx] = fmaxf(y, 0.f);
    }
}

// -------------------------------------------------------------- launch ----
extern "C" void kernel_launch(void* const* d_in, const int* in_sizes, int n_in,
                              void* d_out, int out_size, void* d_ws, size_t ws_size,
                              hipStream_t stream) {
  const float* last  = (const float*)d_in[0];
  const float* cur   = (const float*)d_in[1];
  const float* fut   = (const float*)d_in[2];
  const float* Wqk   = (const float*)d_in[3];
  const float* bqk   = (const float*)d_in[4];
  const float* Wkl   = (const float*)d_in[5];
  const float* bkl   = (const float*)d_in[6];
  const float* Wkf   = (const float*)d_in[7];
  const float* bkf   = (const float*)d_in[8];
  const float* Wv    = (const float*)d_in[9];
  const float* bv    = (const float*)d_in[10];
  const float* Wfire = (const float*)d_in[11];
  const float* bfire = (const float*)d_in[12];
  const float* gamma = (const float*)d_in[13];
  const float* beta  = (const float*)d_in[14];
  const float* mean  = (const float*)d_in[15];
  const float* var   = (const float*)d_in[16];

  char* ws = (char*)d_ws;
  _Float16* qb     = (_Float16*)(ws);                    // [4][64][4096]  2 MB
  _Float16* klb    = (_Float16*)(ws + (2u << 20));       // [4][4096][64]  2 MB
  _Float16* kfb    = (_Float16*)(ws + (4u << 20));       // [4][4096][64]  2 MB
  short*    vb     = (short*)   (ws + (6u << 20));       // [4][64][4096]  2 MB bf16
  _Float16* fusedb = (_Float16*)(ws + (8u << 20));       // [4][4096][128] 4 MB
  char* wsm = ws + (12u << 20);
  _Float16* wqk_h = (_Float16*)(wsm);
  _Float16* wkl_h = (_Float16*)(wsm + (32u << 10));
  _Float16* wkf_h = (_Float16*)(wsm + (64u << 10));
  _Float16* wv_h  = (_Float16*)(wsm + (96u << 10));
  _Float16* wf_h  = (_Float16*)(wsm + (128u << 10));
  float*    scale = (float*)   (wsm + (192u << 10));
  float*    shift = (float*)   (wsm + (193u << 10));
  float*    out   = (float*)d_out;

  prep_kernel<<<128, 256, 0, stream>>>(Wqk, Wkl, Wkf, Wv, Wfire, bfire,
                                       gamma, beta, mean, var,
                                       wqk_h, wkl_h, wkf_h, wv_h, wf_h, scale, shift);
  proj_kernel<<<768, 256, 0, stream>>>(cur, last, fut, wqk_h, bqk, wkl_h, bkl,
                                       wkf_h, bkf, wv_h, bv, qb, klb, kfb, vb);
  attn_kernel<<<512, 256, 0, stream>>>(qb, klb, kfb, vb, fusedb);
  fire_kernel<<<1024, 256, 0, stream>>>(fusedb, wf_h, scale, shift, cur, out);
}

// Round 10
// 204.669 us; speedup vs baseline: 1.3331x; 1.0094x over previous
//
#include <hip/hip_runtime.h>
#include <math.h>
#include <stdint.h>

// B=4, C=256, H=W=64 -> HW=4096, C4=64
#define HWN 4096
#define CIN 256
#define CQ 64
#define LOG2E 1.44269504f
#define C2OFF 56.0f    // fixed softmax offset (exp2 domain); P kept in bf16
                       // (fp32 exponent range) -> tail-query underflow impossible

typedef __attribute__((ext_vector_type(8))) _Float16 f16x8;
typedef __attribute__((ext_vector_type(4))) _Float16 f16x4;
typedef __attribute__((ext_vector_type(8))) short    bf16x8;
typedef __attribute__((ext_vector_type(4))) short    bf16x4;
typedef __attribute__((ext_vector_type(4))) float    f32x4;

__device__ __forceinline__ short f2bf(float f) {
  union { float f; uint32_t u; } c; c.f = f;
  uint32_t r = (c.u + 0x7FFFu + ((c.u >> 16) & 1u)) >> 16;   // RNE
  return (short)(uint16_t)r;
}

// async global->LDS, 16B per lane; LDS dest = wave-uniform base + lane*16.
__device__ __forceinline__ void stage16(const void* g, void* l) {
  __builtin_amdgcn_global_load_lds(
      (const __attribute__((address_space(1))) uint32_t*)g,
      (__attribute__((address_space(3))) uint32_t*)l, 16, 0, 0);
}

// ---------------------------------------------------------------- prep ----
__global__ __launch_bounds__(256) void prep_kernel(
    const float* __restrict__ Wqk, const float* __restrict__ Wkl,
    const float* __restrict__ Wkf, const float* __restrict__ Wv,
    const float* __restrict__ Wfire, const float* __restrict__ bfire,
    const float* __restrict__ gamma, const float* __restrict__ beta,
    const float* __restrict__ mean,  const float* __restrict__ var,
    _Float16* __restrict__ wqk_h, _Float16* __restrict__ wkl_h,
    _Float16* __restrict__ wkf_h, _Float16* __restrict__ wv_h,
    _Float16* __restrict__ wf_h, float* __restrict__ scale, float* __restrict__ shift) {
  int gid = blockIdx.x * 256 + threadIdx.x;
  if (gid < CQ * CIN) {
    wqk_h[gid] = (_Float16)(Wqk[gid] * LOG2E);
    wkl_h[gid] = (_Float16)Wkl[gid];
    wkf_h[gid] = (_Float16)Wkf[gid];
    wv_h[gid]  = (_Float16)Wv[gid];
  }
  if (gid < CIN * 128) wf_h[gid] = (_Float16)Wfire[gid];
  if (gid < CIN) {
    float inv = gamma[gid] / sqrtf(var[gid] + 1e-5f);
    scale[gid] = inv;
    shift[gid] = (bfire[gid] - mean[gid]) * inv + beta[gid];
  }
}

// ---------------------------------------------------------------- proj ----
// 3 passes (block-ranges, grid 768 = 3 blocks/CU). DEEP register prefetch:
// all 64 X-dwords issued before any MFMA (one HBM drain, not 8).
// kl/kf stores go through a wave-private LDS transpose -> coalesced 16B
// stores of [hw][c] rows (R9 scattered 2B at 128B stride).
__global__ __launch_bounds__(256, 3) void proj_kernel(
    const float* __restrict__ cur, const float* __restrict__ last, const float* __restrict__ fut,
    const _Float16* __restrict__ wqk, const float* __restrict__ bqk,
    const _Float16* __restrict__ wkl, const float* __restrict__ bkl,
    const _Float16* __restrict__ wkf, const float* __restrict__ bkf,
    const _Float16* __restrict__ wv,  const float* __restrict__ bv,
    _Float16* __restrict__ q_out, _Float16* __restrict__ kl_out,
    _Float16* __restrict__ kf_out, short* __restrict__ v_out) {
  const int tid  = threadIdx.x;
  const int w    = tid >> 6;
  const int lane = tid & 63;
  const int quad = lane >> 4;
  const int l15  = lane & 15;
  const int pass = blockIdx.x >> 8;
  const int bb   = blockIdx.x & 255;
  const int b    = bb >> 6;
  const int hwt  = (bb & 63) << 6;
  const int hw   = hwt + w * 16 + l15;

  __shared__ __align__(16) _Float16 Tl[4][16][72];   // kl/kf transpose, 9 KB

  const float* X = (pass == 0) ? cur : ((pass == 1) ? last : fut);
  const float* xp = X + (size_t)b * CIN * HWN + hw;

  // ---- deep prefetch: all 64 X values for this lane ----
  float xb[8][8];
#pragma unroll
  for (int c0 = 0; c0 < 8; ++c0)
#pragma unroll
    for (int j = 0; j < 8; ++j)
      xb[c0][j] = xp[(size_t)(c0 * 32 + quad * 8 + j) * HWN];

  if (pass == 0) {
    f32x4 aq[4] = {}; f32x4 av[4] = {};
#pragma unroll
    for (int k0 = 0; k0 < 8; ++k0) {
      f16x8 bh;
#pragma unroll
      for (int j = 0; j < 8; ++j) bh[j] = (_Float16)xb[k0][j];
#pragma unroll
      for (int mt = 0; mt < 4; ++mt) {
        f16x8 wa = *(const f16x8*)(wqk + (mt * 16 + l15) * CIN + k0 * 32 + quad * 8);
        aq[mt] = __builtin_amdgcn_mfma_f32_16x16x32_f16(wa, bh, aq[mt], 0, 0, 0);
        f16x8 wb = *(const f16x8*)(wv + (mt * 16 + l15) * CIN + k0 * 32 + quad * 8);
        av[mt] = __builtin_amdgcn_mfma_f32_16x16x32_f16(wb, bh, av[mt], 0, 0, 0);
      }
    }
#pragma unroll
    for (int mt = 0; mt < 4; ++mt)
#pragma unroll
      for (int r = 0; r < 4; ++r) {
        int oc = mt * 16 + quad * 4 + r;
        q_out[((size_t)b * CQ + oc) * HWN + hw] = (_Float16)(aq[mt][r] + bqk[oc] * LOG2E);
        v_out[((size_t)b * CQ + oc) * HWN + hw] = f2bf(av[mt][r] + bv[oc]);
      }
  } else {
    const _Float16* W = (pass == 1) ? wkl : wkf;
    const float* BI = (pass == 1) ? bkl : bkf;
    _Float16* OUT = (pass == 1) ? kl_out : kf_out;
    f32x4 a[4] = {};
#pragma unroll
    for (int k0 = 0; k0 < 8; ++k0) {
      f16x8 bh;
#pragma unroll
      for (int j = 0; j < 8; ++j) bh[j] = (_Float16)xb[k0][j];
#pragma unroll
      for (int mt = 0; mt < 4; ++mt) {
        f16x8 wa = *(const f16x8*)(W + (mt * 16 + l15) * CIN + k0 * 32 + quad * 8);
        a[mt] = __builtin_amdgcn_mfma_f32_16x16x32_f16(wa, bh, a[mt], 0, 0, 0);
      }
    }
    // transpose via wave-private LDS: b64 writes -> b128 reads -> 16B stores
#pragma unroll
    for (int mt = 0; mt < 4; ++mt) {
      f16x4 pw;
#pragma unroll
      for (int r = 0; r < 4; ++r)
        pw[r] = (_Float16)(a[mt][r] + BI[mt * 16 + quad * 4 + r]);
      *(f16x4*)&Tl[w][l15][mt * 16 + quad * 4] = pw;     // b64
    }
#pragma unroll
    for (int kk = 0; kk < 2; ++kk) {
      f16x8 row = *(const f16x8*)&Tl[w][l15][kk * 32 + quad * 8];   // b128
      *(f16x8*)(OUT + ((size_t)b * HWN + hw) * CQ + kk * 32 + quad * 8) = row;
    }
  }
}

// ---------------------------------------------------------------- attn ----
// (unchanged from R9 — 64q/block, XOR-swizzled async-LDS K/V staging,
//  S^T -> reg exp -> b64/b128 P roundtrip -> K=32 bf16 PV, grid 512)
__global__ __launch_bounds__(256, 2) void attn_kernel(
    const _Float16* __restrict__ qbuf, const _Float16* __restrict__ klbuf,
    const _Float16* __restrict__ kfbuf, const short* __restrict__ vbuf,
    _Float16* __restrict__ fused) {
  const int tid  = threadIdx.x;
  const int w    = tid >> 6;
  const int lane = tid & 63;
  const int quad = lane >> 4;
  const int l15  = lane & 15;
  const int bx   = blockIdx.x;
  const int pair = bx & 1;
  const int b    = (bx >> 1) & 3;
  const int qt   = (bx >> 3) << 6;          // 64 queries per block

  const _Float16* K  = (pair ? kfbuf : klbuf) + (size_t)b * HWN * CQ;  // [key][c]
  const short*    Vg = vbuf + (size_t)b * CQ * HWN;                    // [c][key]

  __shared__ __align__(16) _Float16 Kt[2][64][64];   // [buf][key][c]   16 KB
  __shared__ __align__(16) short    Vt[2][64][64];   // [buf][c][key]   16 KB
  __shared__ __align__(16) short    Pl[4][16][72];   //                  9 KB

  const int qbase = qt + w * 16;
  f16x8 qfrag[2];
#pragma unroll
  for (int kk = 0; kk < 2; ++kk)
#pragma unroll
    for (int j = 0; j < 8; ++j)
      qfrag[kk][j] = qbuf[(b * CQ + kk * 32 + quad * 8 + j) * HWN + qbase + l15];

  f32x4 Oacc[4] = {};          // [ct]: row=q(quad*4+r), col=c4(ct*16+l15)
  float psum = 0.f;            // per-lane partial (q=l15, this quad's keys)

  const int swz = (lane & 7) ^ ((lane >> 3) & 7);    // staging source chunk
  const int rswz = l15 & 7;                          // reader XOR key

  auto stageK = [&](int buf, int t) {
#pragma unroll
    for (int r = 0; r < 2; ++r)
      stage16(K + (size_t)(t * 64 + w * 16 + r * 8 + (lane >> 3)) * CQ + swz * 8,
              &Kt[buf][w * 16 + r * 8][0]);
  };
  auto stageV = [&](int buf, int t) {
#pragma unroll
    for (int r = 0; r < 2; ++r)
      stage16(Vg + (size_t)(w * 16 + r * 8 + (lane >> 3)) * HWN + t * 64 + swz * 8,
              &Vt[buf][w * 16 + r * 8][0]);
  };

  auto body = [&](int buf) {
    f16x8 kf[4][2];
#pragma unroll
    for (int nt = 0; nt < 4; ++nt)
#pragma unroll
      for (int kk = 0; kk < 2; ++kk)
        kf[nt][kk] = *(const f16x8*)&Kt[buf][nt * 16 + l15][((kk * 4 + quad) ^ rswz) * 8];
    bf16x8 vf[4][2];
#pragma unroll
    for (int ct = 0; ct < 4; ++ct)
#pragma unroll
      for (int kk = 0; kk < 2; ++kk)
        vf[ct][kk] = *(const bf16x8*)&Vt[buf][ct * 16 + l15][((kk * 4 + quad) ^ rswz) * 8];
    f32x4 ST[4] = {};
#pragma unroll
    for (int nt = 0; nt < 4; ++nt)
#pragma unroll
      for (int kk = 0; kk < 2; ++kk)
        ST[nt] = __builtin_amdgcn_mfma_f32_16x16x32_f16(kf[nt][kk], qfrag[kk], ST[nt], 0, 0, 0);
#pragma unroll
    for (int nt = 0; nt < 4; ++nt) {
      bf16x4 pw;
#pragma unroll
      for (int r = 0; r < 4; ++r) {
        float p = __builtin_amdgcn_exp2f(ST[nt][r] - C2OFF);
        uint32_t u = __float_as_uint(p) & 0xffff0000u;   // truncate to bf16
        psum += __uint_as_float(u);                      // consistent with P
        pw[r] = (short)(u >> 16);
      }
      *(bf16x4*)&Pl[w][l15][nt * 16 + quad * 4] = pw;    // b64
    }
#pragma unroll
    for (int kk = 0; kk < 2; ++kk) {
      bf16x8 pf = *(const bf16x8*)&Pl[w][l15][kk * 32 + quad * 8];  // b128
#pragma unroll
      for (int ct = 0; ct < 4; ++ct)
        Oacc[ct] = __builtin_amdgcn_mfma_f32_16x16x32_bf16(pf, vf[ct][kk], Oacc[ct], 0, 0, 0);
    }
  };

  stageK(0, 0); stageV(0, 0);
  __syncthreads();
#pragma unroll 1
  for (int tt = 0; tt < 64; tt += 2) {
    stageK(1, tt + 1); stageV(1, tt + 1);     // tt+1 <= 63 always
    body(0);
    __syncthreads();                           // drains staging of tt+1
    if (tt + 2 < 64) { stageK(0, tt + 2); stageV(0, tt + 2); }
    body(1);
    __syncthreads();
  }

  psum += __shfl_xor(psum, 16);
  psum += __shfl_xor(psum, 32);

#pragma unroll
  for (int r = 0; r < 4; ++r) {
    float lt = __shfl(psum, quad * 4 + r);     // row-sum lives at lane q
    float invl = __builtin_amdgcn_rcpf(lt);
    int qi = qbase + quad * 4 + r;
#pragma unroll
    for (int ct = 0; ct < 4; ++ct)
      fused[((size_t)b * HWN + qi) * 128 + pair * 64 + ct * 16 + l15] =
          (_Float16)(Oacc[ct][r] * invl);
  }
}

// ---------------------------------------------------------------- fire ----
// Wave = 16 hw x 64 oc; grid 1024. All HBM loads issued before MFMAs.
__global__ __launch_bounds__(256) void fire_kernel(
    const _Float16* __restrict__ fused, const _Float16* __restrict__ wf,
    const float* __restrict__ scale, const float* __restrict__ shift,
    const float* __restrict__ cur, float* __restrict__ out) {
  const int tid  = threadIdx.x;
  const int w    = tid >> 6;
  const int lane = tid & 63;
  const int quad = lane >> 4;
  const int l15  = lane & 15;
  const int g    = blockIdx.x & 3;
  const int bb   = blockIdx.x >> 2;
  const int b    = bb >> 6;
  const int hwt  = (bb & 63) << 6;
  const int hwb  = hwt + w * 16;

  f16x8 bfr[4];
#pragma unroll
  for (int k0 = 0; k0 < 4; ++k0)
    bfr[k0] = *(const f16x8*)(fused + ((size_t)b * HWN + hwb + l15) * 128 + k0 * 32 + quad * 8);

  float curv[4][4];
#pragma unroll
  for (int mt = 0; mt < 4; ++mt)
#pragma unroll
    for (int r = 0; r < 4; ++r)
      curv[mt][r] = cur[((size_t)b * CIN + g * 64 + mt * 16 + quad * 4 + r) * HWN + hwb + l15];

  f32x4 acc[4] = {};
#pragma unroll
  for (int k0 = 0; k0 < 4; ++k0)
#pragma unroll
    for (int mt = 0; mt < 4; ++mt) {
      f16x8 af = *(const f16x8*)(wf + (g * 64 + mt * 16 + l15) * 128 + k0 * 32 + quad * 8);
      acc[mt] = __builtin_amdgcn_mfma_f32_16x16x32_f16(af, bfr[k0], acc[mt], 0, 0, 0);
    }

#pragma unroll
  for (int mt = 0; mt < 4; ++mt)
#pragma unroll
    for (int r = 0; r < 4; ++r) {
      int oc = g * 64 + mt * 16 + quad * 4 + r;
      size_t idx = ((size_t)b * CIN + oc) * HWN + hwb + l15;
      float y = curv[mt][r] + acc[mt][r] * scale[oc] + shift[oc];
      out[idx] = fmaxf(y, 0.f);
    }
}

// -------------------------------------------------------------- launch ----
extern "C" void kernel_launch(void* const* d_in, const int* in_sizes, int n_in,
                              void* d_out, int out_size, void* d_ws, size_t ws_size,
                              hipStream_t stream) {
  const float* last  = (const float*)d_in[0];
  const float* cur   = (const float*)d_in[1];
  const float* fut   = (const float*)d_in[2];
  const float* Wqk   = (const float*)d_in[3];
  const float* bqk   = (const float*)d_in[4];
  const float* Wkl   = (const float*)d_in[5];
  const float* bkl   = (const float*)d_in[6];
  const float* Wkf   = (const float*)d_in[7];
  const float* bkf   = (const float*)d_in[8];
  const float* Wv    = (const float*)d_in[9];
  const float* bv    = (const float*)d_in[10];
  const float* Wfire = (const float*)d_in[11];
  const float* bfire = (const float*)d_in[12];
  const float* gamma = (const float*)d_in[13];
  const float* beta  = (const float*)d_in[14];
  const float* mean  = (const float*)d_in[15];
  const float* var   = (const float*)d_in[16];

  char* ws = (char*)d_ws;
  _Float16* qb     = (_Float16*)(ws);                    // [4][64][4096]  2 MB
  _Float16* klb    = (_Float16*)(ws + (2u << 20));       // [4][4096][64]  2 MB
  _Float16* kfb    = (_Float16*)(ws + (4u << 20));       // [4][4096][64]  2 MB
  short*    vb     = (short*)   (ws + (6u << 20));       // [4][64][4096]  2 MB bf16
  _Float16* fusedb = (_Float16*)(ws + (8u << 20));       // [4][4096][128] 4 MB
  char* wsm = ws + (12u << 20);
  _Float16* wqk_h = (_Float16*)(wsm);
  _Float16* wkl_h = (_Float16*)(wsm + (32u << 10));
  _Float16* wkf_h = (_Float16*)(wsm + (64u << 10));
  _Float16* wv_h  = (_Float16*)(wsm + (96u << 10));
  _Float16* wf_h  = (_Float16*)(wsm + (128u << 10));
  float*    scale = (float*)   (wsm + (192u << 10));
  float*    shift = (float*)   (wsm + (193u << 10));
  float*    out   = (float*)d_out;

  prep_kernel<<<128, 256, 0, stream>>>(Wqk, Wkl, Wkf, Wv, Wfire, bfire,
                                       gamma, beta, mean, var,
                                       wqk_h, wkl_h, wkf_h, wv_h, wf_h, scale, shift);
  proj_kernel<<<768, 256, 0, stream>>>(cur, last, fut, wqk_h, bqk, wkl_h, bkl,
                                       wkf_h, bkf, wv_h, bv, qb, klb, kfb, vb);
  attn_kernel<<<512, 256, 0, stream>>>(qb, klb, kfb, vb, fusedb);
  fire_kernel<<<1024, 256, 0, stream>>>(fusedb, wf_h, scale, shift, cur, out);
}